// Round 6
// baseline (845.213 us; speedup 1.0000x reference)
//
#include <hip/hip_runtime.h>

typedef float f32x4 __attribute__((ext_vector_type(4)));

#define EPS 1e-8f

constexpr int D = 384;
constexpr int P = 16;                         // parts per i-slab
constexpr int UNITS = D * P;                  // 6144
constexpr int Q_PER_I = (D * D) / 4;          // 36864 float4 per i-slab
constexpr int Q_PER_UNIT = Q_PER_I / P;       // 2304 float4 per unit
constexpr int THREADS = 256;
constexpr int ITERS = Q_PER_UNIT / THREADS;   // 9
constexpr int J_PER_UNIT = D / P;             // 24 j-rows per unit
constexpr int GRID = 2048;                    // 8 blocks/CU -> all co-resident
constexpr int UNITS_PER_BLOCK = UNITS / GRID; // 3 (contiguous per block)
constexpr int WAVES_TOTAL = GRID * (THREADS / 64); // 8192
// 65536 rows / 8192 waves = 8 rows per wave, exact.

__global__ __launch_bounds__(THREADS, 8) void fused_kernel(
    const float* __restrict__ x,
    const float* __restrict__ y,
    const float* __restrict__ z,
    const float* __restrict__ a,
    float* __restrict__ partials,
    unsigned int* __restrict__ done,
    float* __restrict__ out,
    int N) {
  const int b = blockIdx.x;
  const int tid = threadIdx.x;
  const int lane = tid & 63;
  const int w = tid >> 6;

  __shared__ float sm[THREADS / 64];
  __shared__ float ctx_s[D];

  const f32x4* z4 = reinterpret_cast<const f32x4*>(z);
  const f32x4* x4 = reinterpret_cast<const f32x4*>(x);

  // ---- phase A: reduce 3 contiguous units of a -> partials ----
#pragma unroll
  for (int ui = 0; ui < UNITS_PER_BLOCK; ++ui) {
    const int unit = b * UNITS_PER_BLOCK + ui;      // 0..6143, contiguous
    const int i = unit >> 4;                        // unit / 16
    const int part = unit & 15;                     // unit % 16
    const f32x4* a4 = reinterpret_cast<const f32x4*>(a) +
                      (size_t)i * Q_PER_I + (size_t)part * Q_PER_UNIT;
    const int jbase = part * J_PER_UNIT;

    float acc = 0.0f;
#pragma unroll 3
    for (int it = 0; it < ITERS; ++it) {
      int q = it * THREADS + tid;                   // [0, 2304)
      int jl = q / 96;                              // 0..23 (magic-mul div)
      int k4 = q - jl * 96;                         // 0..95
      f32x4 av = a4[q];
      f32x4 zv = z4[k4];
      float yj = y[jbase + jl];
      acc += yj * (av.x * zv.x + av.y * zv.y + av.z * zv.z + av.w * zv.w);
    }
    for (int off = 32; off > 0; off >>= 1)
      acc += __shfl_down(acc, off);
    if (lane == 0) sm[w] = acc;
    __syncthreads();
    if (tid == 0) {
      float s = 0.0f;
#pragma unroll
      for (int k = 0; k < THREADS / 64; ++k) s += sm[k];
      partials[unit] = s;
    }
    __syncthreads();
  }

  // ---- signal: release our partials to agent scope ----
  __threadfence();
  if (tid == 0)
    __hip_atomic_fetch_add(done, 1u, __ATOMIC_RELEASE, __HIP_MEMORY_SCOPE_AGENT);

  // ---- prefetch first 2 x-rows into registers while others finish ----
  const int waveId = b * (THREADS / 64) + w;
  const int r0 = waveId;
  const int r1 = waveId + WAVES_TOTAL;
  f32x4 xa0 = x4[(size_t)r0 * 96 + lane];
  f32x4 xa1 = x4[(size_t)r1 * 96 + lane];
  f32x4 xb0 = {0.f, 0.f, 0.f, 0.f}, xb1 = {0.f, 0.f, 0.f, 0.f};
  if (lane < 32) {
    xb0 = x4[(size_t)r0 * 96 + 64 + lane];
    xb1 = x4[(size_t)r1 * 96 + 64 + lane];
  }

  // ---- global barrier: spin until all 2048 blocks signaled ----
  if (tid == 0) {
    while (__hip_atomic_load(done, __ATOMIC_ACQUIRE, __HIP_MEMORY_SCOPE_AGENT) <
           (unsigned int)GRID)
      __builtin_amdgcn_s_sleep(8);
  }
  __syncthreads();
  __threadfence();  // acquire side: ensure no stale partials from caches

  // ---- fold partials -> ctx in LDS ----
  const f32x4* p4 = reinterpret_cast<const f32x4*>(partials);
  for (int t = tid; t < D; t += THREADS) {
    f32x4 s0 = p4[t * 4 + 0];
    f32x4 s1 = p4[t * 4 + 1];
    f32x4 s2 = p4[t * 4 + 2];
    f32x4 s3 = p4[t * 4 + 3];
    ctx_s[t] = (s0.x + s0.y + s0.z + s0.w) + (s1.x + s1.y + s1.z + s1.w) +
               (s2.x + s2.y + s2.z + s2.w) + (s3.x + s3.y + s3.z + s3.w);
  }
  __syncthreads();

  const float scale = 1.0f / (ctx_s[0] + EPS);
  const f32x4* c4 = reinterpret_cast<const f32x4*>(ctx_s);
  const f32x4 cv = c4[lane];
  f32x4 cv2 = {0.f, 0.f, 0.f, 0.f};
  if (lane < 32) cv2 = c4[64 + lane];

  // ---- phase C: 8 rows per wave; rows 0,1 from prefetched registers ----
  {
    float s = xa0.x * cv.x + xa0.y * cv.y + xa0.z * cv.z + xa0.w * cv.w;
    if (lane < 32)
      s += xb0.x * cv2.x + xb0.y * cv2.y + xb0.z * cv2.z + xb0.w * cv2.w;
    for (int off = 32; off > 0; off >>= 1) s += __shfl_down(s, off);
    if (lane == 0) out[r0] = s * scale;
  }
  {
    float s = xa1.x * cv.x + xa1.y * cv.y + xa1.z * cv.z + xa1.w * cv.w;
    if (lane < 32)
      s += xb1.x * cv2.x + xb1.y * cv2.y + xb1.z * cv2.z + xb1.w * cv2.w;
    for (int off = 32; off > 0; off >>= 1) s += __shfl_down(s, off);
    if (lane == 0) out[r1] = s * scale;
  }
  for (int row = waveId + 2 * WAVES_TOTAL; row < N; row += WAVES_TOTAL) {
    f32x4 xa = x4[(size_t)row * 96 + lane];
    float s = xa.x * cv.x + xa.y * cv.y + xa.z * cv.z + xa.w * cv.w;
    if (lane < 32) {
      f32x4 xb = x4[(size_t)row * 96 + 64 + lane];
      s += xb.x * cv2.x + xb.y * cv2.y + xb.z * cv2.z + xb.w * cv2.w;
    }
    for (int off = 32; off > 0; off >>= 1) s += __shfl_down(s, off);
    if (lane == 0) out[row] = s * scale;
  }
}

extern "C" void kernel_launch(void* const* d_in, const int* in_sizes, int n_in,
                              void* d_out, int out_size, void* d_ws, size_t ws_size,
                              hipStream_t stream) {
  const float* x = (const float*)d_in[0];  // [N, 384]
  const float* y = (const float*)d_in[1];  // [384]
  const float* z = (const float*)d_in[2];  // [384]
  const float* a = (const float*)d_in[3];  // [384, 384, 384]
  float* out = (float*)d_out;              // [N]

  int N = in_sizes[0] / D;                 // 65536

  float* partials = (float*)d_ws;                       // UNITS floats
  unsigned int* done = (unsigned int*)(partials + UNITS); // 1 uint

  // Reset the barrier counter every call (ws is not re-poisoned between
  // graph replays; counter must start at 0). Memset node is graph-legal.
  hipMemsetAsync(done, 0, sizeof(unsigned int), stream);

  void* args_unused = nullptr; (void)args_unused;
  fused_kernel<<<GRID, THREADS, 0, stream>>>(x, y, z, a, partials, done, out, N);
}

// Round 7
// 60.311 us; speedup vs baseline: 14.0142x; 14.0142x over previous
//
#include <hip/hip_runtime.h>

typedef float f32x4 __attribute__((ext_vector_type(4)));

#define EPS 1e-8f

constexpr int D = 384;
constexpr int Q_PER_I = (D * D) / 4;        // 36864 float4 per i-slab
constexpr int P = 4;                        // partial blocks per i
constexpr int Q_PER_PART = Q_PER_I / P;     // 9216 float4 per block slab (144 KB)
constexpr int THREADS_A = 256;
constexpr int ITERS_A = Q_PER_PART / THREADS_A; // 36 (12 groups of 3)
constexpr int J_PER_PART = 96;              // j-rows per part

// Kernel A: partials[i*P+part] = sum over a[i, jbase:jbase+96, :] * y[j] * z[k]
// 1536 blocks (6/CU), each reads a contiguous 144 KB slab of a.
// Inner loop strength-reduced: z values are periodic (period 3 in the iter
// index since 256 mod 96 = 64), y-row index advances by a fixed per-thread
// increment pattern -> no integer division in the loop, 1 HBM load/iter.
__global__ __launch_bounds__(THREADS_A) void ctx_partial_kernel(
    const float* __restrict__ a,
    const float* __restrict__ y,
    const float* __restrict__ z,
    float* __restrict__ partials) {
  const int b = blockIdx.x;
  const int i = b >> 2;                     // b / P
  const int part = b & 3;                   // b % P
  const f32x4* a4 = reinterpret_cast<const f32x4*>(a) +
                    (size_t)i * Q_PER_I + (size_t)part * Q_PER_PART;
  const f32x4* z4 = reinterpret_cast<const f32x4*>(z);
  const int tid = threadIdx.x;
  const float* yb = y + part * J_PER_PART;

  // initial row/col decomposition of q = tid
  int jl = tid / 96;                        // 0..2 (one divide, outside loop)
  const int k4 = tid - jl * 96;             // 0..95
  int k4b = k4 + 64; if (k4b >= 96) k4b -= 96;
  int k4c = k4b + 64; if (k4c >= 96) k4c -= 96;
  const f32x4 zva = z4[k4];
  const f32x4 zvb = z4[k4b];
  const f32x4 zvc = z4[k4c];
  const int incA = (k4 >= 32) ? 3 : 2;      // jl step after phase a
  const int incAB = incA + ((k4b >= 32) ? 3 : 2); // cumulative after phase b
  // over 3 iters q advances 768 = 8*96 -> jl advances exactly 8

  const f32x4* ap = a4 + tid;
  float acc = 0.0f;
#pragma unroll 4
  for (int g = 0; g < ITERS_A / 3; ++g) {   // 12 groups
    f32x4 av0 = ap[0 * THREADS_A];
    f32x4 av1 = ap[1 * THREADS_A];
    f32x4 av2 = ap[2 * THREADS_A];
    float ya = yb[jl];
    float yB = yb[jl + incA];
    float yC = yb[jl + incAB];
    acc += ya * (av0.x * zva.x + av0.y * zva.y + av0.z * zva.z + av0.w * zva.w);
    acc += yB * (av1.x * zvb.x + av1.y * zvb.y + av1.z * zvb.z + av1.w * zvb.w);
    acc += yC * (av2.x * zvc.x + av2.y * zvc.y + av2.z * zvc.z + av2.w * zvc.w);
    ap += 3 * THREADS_A;
    jl += 8;
  }

  for (int off = 32; off > 0; off >>= 1)
    acc += __shfl_down(acc, off);

  __shared__ float sm[THREADS_A / 64];
  const int lane = tid & 63;
  const int w = tid >> 6;
  if (lane == 0) sm[w] = acc;
  __syncthreads();
  if (tid == 0) {
    float s = 0.0f;
#pragma unroll
    for (int k = 0; k < THREADS_A / 64; ++k) s += sm[k];
    partials[b] = s;
  }
}

// Kernel C: fold partials (P=4 -> one float4 per i) into ctx in LDS, then
// grid-stride matvec: 2048 blocks x 256 threads, 1 row per wave per iter.
__global__ __launch_bounds__(256) void score_kernel(
    const float* __restrict__ x,
    const float* __restrict__ partials,
    float* __restrict__ out,
    int N) {
  __shared__ float ctx_s[D];
  const int tid = threadIdx.x;

  const f32x4* p4 = reinterpret_cast<const f32x4*>(partials);
  for (int t = tid; t < D; t += 256) {
    f32x4 v = p4[t];
    ctx_s[t] = v.x + v.y + v.z + v.w;
  }
  __syncthreads();

  const float scale = 1.0f / (ctx_s[0] + EPS);
  const int lane = tid & 63;
  const int w = tid >> 6;
  const f32x4* c4 = reinterpret_cast<const f32x4*>(ctx_s);
  const f32x4 cv = c4[lane];
  f32x4 cv2 = {0.f, 0.f, 0.f, 0.f};
  if (lane < 32) cv2 = c4[64 + lane];

  const f32x4* x4 = reinterpret_cast<const f32x4*>(x);
  const int waveId = blockIdx.x * 4 + w;
  const int totalWaves = gridDim.x * 4;
  for (int row = waveId; row < N; row += totalWaves) {
    const f32x4* xr = x4 + (size_t)row * (D / 4);
    f32x4 xv = xr[lane];
    float s = xv.x * cv.x + xv.y * cv.y + xv.z * cv.z + xv.w * cv.w;
    if (lane < 32) {
      f32x4 xv2 = xr[64 + lane];
      s += xv2.x * cv2.x + xv2.y * cv2.y + xv2.z * cv2.z + xv2.w * cv2.w;
    }
    for (int off = 32; off > 0; off >>= 1)
      s += __shfl_down(s, off);
    if (lane == 0) out[row] = s * scale;
  }
}

extern "C" void kernel_launch(void* const* d_in, const int* in_sizes, int n_in,
                              void* d_out, int out_size, void* d_ws, size_t ws_size,
                              hipStream_t stream) {
  const float* x = (const float*)d_in[0];  // [N, 384]
  const float* y = (const float*)d_in[1];  // [384]
  const float* z = (const float*)d_in[2];  // [384]
  const float* a = (const float*)d_in[3];  // [384, 384, 384]
  float* out = (float*)d_out;              // [N]

  const int N = in_sizes[0] / D;           // 65536
  float* partials = (float*)d_ws;          // D*P floats

  ctx_partial_kernel<<<D * P, THREADS_A, 0, stream>>>(a, y, z, partials);
  score_kernel<<<2048, 256, 0, stream>>>(x, partials, out, N);
}

// Round 8
// 55.832 us; speedup vs baseline: 15.1386x; 1.0802x over previous
//
#include <hip/hip_runtime.h>

typedef float f32x4 __attribute__((ext_vector_type(4)));

#define EPS 1e-8f

constexpr int D = 384;
constexpr int Q_PER_I = (D * D) / 4;        // 36864 float4 per i-slab
constexpr int P = 8;                        // parts per i
constexpr int Q_PER_PART = Q_PER_I / P;     // 4608 float4 per block slab (72 KB)
constexpr int THREADS_A = 256;
constexpr int ITERS_A = Q_PER_PART / THREADS_A; // 18 (6 groups of 3)
constexpr int J_PER_PART = D / P;           // 48 j-rows per part

__device__ __forceinline__ f32x4 ldnt(const f32x4* p) {
  return __builtin_nontemporal_load(p);
}

// Kernel A: partials[b] = sum over a[i, jbase:jbase+48, :] * y[j] * z[k]
// 3072 blocks (12/CU queued, 8 resident = 32 waves/CU), contiguous 72 KB slabs,
// non-temporal a-loads (read-once; don't allocate in L2).
__global__ __launch_bounds__(THREADS_A) void ctx_partial_kernel(
    const float* __restrict__ a,
    const float* __restrict__ y,
    const float* __restrict__ z,
    float* __restrict__ partials) {
  const int b = blockIdx.x;
  const int i = b >> 3;                     // b / P
  const int part = b & 7;                   // b % P
  const f32x4* a4 = reinterpret_cast<const f32x4*>(a) +
                    (size_t)i * Q_PER_I + (size_t)part * Q_PER_PART;
  const f32x4* z4 = reinterpret_cast<const f32x4*>(z);
  const int tid = threadIdx.x;
  const float* yb = y + part * J_PER_PART;

  // q = tid + it*256; k4 = q mod 96 has period 3; jl advances 8 per group.
  int jl = tid / 96;                        // 0..2
  const int k4 = tid - jl * 96;             // 0..95
  int k4b = k4 + 64; if (k4b >= 96) k4b -= 96;
  int k4c = k4b + 64; if (k4c >= 96) k4c -= 96;
  const f32x4 zva = z4[k4];
  const f32x4 zvb = z4[k4b];
  const f32x4 zvc = z4[k4c];
  const int incA = (k4 >= 32) ? 3 : 2;
  const int incAB = incA + ((k4b >= 32) ? 3 : 2);

  const f32x4* ap = a4 + tid;
  float acc = 0.0f;
#pragma unroll
  for (int g = 0; g < ITERS_A / 3; ++g) {   // 6 groups
    f32x4 av0 = ldnt(ap + 0 * THREADS_A);
    f32x4 av1 = ldnt(ap + 1 * THREADS_A);
    f32x4 av2 = ldnt(ap + 2 * THREADS_A);
    float ya = yb[jl];
    float yB = yb[jl + incA];
    float yC = yb[jl + incAB];
    acc += ya * (av0.x * zva.x + av0.y * zva.y + av0.z * zva.z + av0.w * zva.w);
    acc += yB * (av1.x * zvb.x + av1.y * zvb.y + av1.z * zvb.z + av1.w * zvb.w);
    acc += yC * (av2.x * zvc.x + av2.y * zvc.y + av2.z * zvc.z + av2.w * zvc.w);
    ap += 3 * THREADS_A;
    jl += 8;
  }

  for (int off = 32; off > 0; off >>= 1)
    acc += __shfl_down(acc, off);

  __shared__ float sm[THREADS_A / 64];
  const int lane = tid & 63;
  const int w = tid >> 6;
  if (lane == 0) sm[w] = acc;
  __syncthreads();
  if (tid == 0) {
    float s = 0.0f;
#pragma unroll
    for (int k = 0; k < THREADS_A / 64; ++k) s += sm[k];
    partials[b] = s;
  }
}

// Kernel C: fold partials (P=8 per i) -> ctx in LDS, then grid-stride matvec.
// 2048 blocks x 256 (8 blocks/CU = 32 waves/CU), 8 rows/wave processed in
// pairs (2 independent shuffle chains per iteration), NT x-loads.
__global__ __launch_bounds__(256) void score_kernel(
    const float* __restrict__ x,
    const float* __restrict__ partials,
    float* __restrict__ out,
    int N) {
  __shared__ float ctx_s[D];
  const int tid = threadIdx.x;

  const f32x4* p4 = reinterpret_cast<const f32x4*>(partials);
  for (int t = tid; t < D; t += 256) {
    f32x4 v0 = p4[t * 2 + 0];
    f32x4 v1 = p4[t * 2 + 1];
    ctx_s[t] = (v0.x + v0.y + v0.z + v0.w) + (v1.x + v1.y + v1.z + v1.w);
  }
  __syncthreads();

  const float scale = 1.0f / (ctx_s[0] + EPS);
  const int lane = tid & 63;
  const int w = tid >> 6;
  const f32x4* c4 = reinterpret_cast<const f32x4*>(ctx_s);
  const f32x4 cv = c4[lane];
  f32x4 cv2 = {0.f, 0.f, 0.f, 0.f};
  if (lane < 32) cv2 = c4[64 + lane];

  const f32x4* x4 = reinterpret_cast<const f32x4*>(x);
  const int waveId = blockIdx.x * 4 + w;
  const int totalWaves = gridDim.x * 4;       // 8192

  int row = waveId;
  while (row + totalWaves < N) {
    const int r0 = row;
    const int r1 = row + totalWaves;
    const f32x4* xr0 = x4 + (size_t)r0 * 96;
    const f32x4* xr1 = x4 + (size_t)r1 * 96;
    f32x4 xa0 = ldnt(xr0 + lane);
    f32x4 xa1 = ldnt(xr1 + lane);
    f32x4 xb0 = {0.f, 0.f, 0.f, 0.f}, xb1 = {0.f, 0.f, 0.f, 0.f};
    if (lane < 32) {
      xb0 = ldnt(xr0 + 64 + lane);
      xb1 = ldnt(xr1 + 64 + lane);
    }
    float s0 = xa0.x * cv.x + xa0.y * cv.y + xa0.z * cv.z + xa0.w * cv.w;
    float s1 = xa1.x * cv.x + xa1.y * cv.y + xa1.z * cv.z + xa1.w * cv.w;
    if (lane < 32) {
      s0 += xb0.x * cv2.x + xb0.y * cv2.y + xb0.z * cv2.z + xb0.w * cv2.w;
      s1 += xb1.x * cv2.x + xb1.y * cv2.y + xb1.z * cv2.z + xb1.w * cv2.w;
    }
#pragma unroll
    for (int off = 32; off > 0; off >>= 1) {
      s0 += __shfl_down(s0, off);
      s1 += __shfl_down(s1, off);
    }
    if (lane == 0) {
      out[r0] = s0 * scale;
      out[r1] = s1 * scale;
    }
    row += 2 * totalWaves;
  }
  // tail (only if N not a multiple of 2*totalWaves rows-per-wave pattern)
  if (row < N) {
    const f32x4* xr = x4 + (size_t)row * 96;
    f32x4 xa = ldnt(xr + lane);
    float s = xa.x * cv.x + xa.y * cv.y + xa.z * cv.z + xa.w * cv.w;
    if (lane < 32) {
      f32x4 xb = ldnt(xr + 64 + lane);
      s += xb.x * cv2.x + xb.y * cv2.y + xb.z * cv2.z + xb.w * cv2.w;
    }
#pragma unroll
    for (int off = 32; off > 0; off >>= 1) s += __shfl_down(s, off);
    if (lane == 0) out[row] = s * scale;
  }
}

extern "C" void kernel_launch(void* const* d_in, const int* in_sizes, int n_in,
                              void* d_out, int out_size, void* d_ws, size_t ws_size,
                              hipStream_t stream) {
  const float* x = (const float*)d_in[0];  // [N, 384]
  const float* y = (const float*)d_in[1];  // [384]
  const float* z = (const float*)d_in[2];  // [384]
  const float* a = (const float*)d_in[3];  // [384, 384, 384]
  float* out = (float*)d_out;              // [N]

  const int N = in_sizes[0] / D;           // 65536
  float* partials = (float*)d_ws;          // D*P floats

  ctx_partial_kernel<<<D * P, THREADS_A, 0, stream>>>(a, y, z, partials);
  score_kernel<<<2048, 256, 0, stream>>>(x, partials, out, N);
}

// Round 9
// 54.248 us; speedup vs baseline: 15.5805x; 1.0292x over previous
//
#include <hip/hip_runtime.h>

typedef float f32x4 __attribute__((ext_vector_type(4)));

#define EPS 1e-8f

constexpr int D = 384;
constexpr int Q_PER_I = (D * D) / 4;        // 36864 float4 per i-slab
constexpr int P = 8;                        // parts per i
constexpr int Q_PER_PART = Q_PER_I / P;     // 4608 float4 per block slab (72 KB)
constexpr int THREADS_A = 256;
constexpr int ITERS_A = Q_PER_PART / THREADS_A; // 18 = 3 groups of 6
constexpr int J_PER_PART = D / P;           // 48 j-rows per part

__device__ __forceinline__ f32x4 ldnt(const f32x4* p) {
  return __builtin_nontemporal_load(p);
}
__device__ __forceinline__ float dot4(f32x4 a, f32x4 b) {
  return a.x * b.x + a.y * b.y + a.z * b.z + a.w * b.w;
}

// Kernel A: partials[b] = sum over a[i, jbase:jbase+48, :] * y[j] * z[k]
// 3072 blocks, 6 NT loads in flight per lane, VGPR capped for 8 waves/EU.
__global__ __launch_bounds__(THREADS_A, 8) void ctx_partial_kernel(
    const float* __restrict__ a,
    const float* __restrict__ y,
    const float* __restrict__ z,
    float* __restrict__ partials) {
  const int b = blockIdx.x;
  const int i = b >> 3;
  const int part = b & 7;
  const f32x4* a4 = reinterpret_cast<const f32x4*>(a) +
                    (size_t)i * Q_PER_I + (size_t)part * Q_PER_PART;
  const f32x4* z4 = reinterpret_cast<const f32x4*>(z);
  const int tid = threadIdx.x;
  const float* yb = y + part * J_PER_PART;

  // q = tid + it*256; k4 = q mod 96 has period 3; jl advances 16 per group of 6.
  int jl = tid / 96;                        // 0..2
  const int k4 = tid - jl * 96;             // 0..95
  int k4b = k4 + 64; if (k4b >= 96) k4b -= 96;
  int k4c = k4b + 64; if (k4c >= 96) k4c -= 96;
  const f32x4 zva = z4[k4];
  const f32x4 zvb = z4[k4b];
  const f32x4 zvc = z4[k4c];
  const int incA = (k4 >= 32) ? 3 : 2;
  const int incAB = incA + ((k4b >= 32) ? 3 : 2);

  const f32x4* ap = a4 + tid;
  float acc = 0.0f;
#pragma unroll
  for (int g = 0; g < ITERS_A / 6; ++g) {   // 3 groups of 6
    f32x4 av0 = ldnt(ap + 0 * THREADS_A);
    f32x4 av1 = ldnt(ap + 1 * THREADS_A);
    f32x4 av2 = ldnt(ap + 2 * THREADS_A);
    f32x4 av3 = ldnt(ap + 3 * THREADS_A);
    f32x4 av4 = ldnt(ap + 4 * THREADS_A);
    f32x4 av5 = ldnt(ap + 5 * THREADS_A);
    float y0 = yb[jl];
    float y1 = yb[jl + incA];
    float y2 = yb[jl + incAB];
    float y3 = yb[jl + 8];
    float y4 = yb[jl + 8 + incA];
    float y5 = yb[jl + 8 + incAB];
    acc += y0 * dot4(av0, zva);
    acc += y1 * dot4(av1, zvb);
    acc += y2 * dot4(av2, zvc);
    acc += y3 * dot4(av3, zva);
    acc += y4 * dot4(av4, zvb);
    acc += y5 * dot4(av5, zvc);
    ap += 6 * THREADS_A;
    jl += 16;
  }

  for (int off = 32; off > 0; off >>= 1)
    acc += __shfl_down(acc, off);

  __shared__ float sm[THREADS_A / 64];
  const int lane = tid & 63;
  const int w = tid >> 6;
  if (lane == 0) sm[w] = acc;
  __syncthreads();
  if (tid == 0) {
    float s = 0.0f;
#pragma unroll
    for (int k = 0; k < THREADS_A / 64; ++k) s += sm[k];
    partials[b] = s;
  }
}

// Kernel C: fold partials -> ctx in LDS, then matvec. Each wave owns 8
// ADJACENT rows; a row-pair is 192 float4 = exactly 3 full-width loads/lane.
// 2 pairs (6 NT loads) in flight per iteration. No idle lanes on loads.
// Lane l covers: pair combined idx pA=l (row0 col l), pB=l+64
// (l<32: row0 col l+64 ; l>=32: row1 col l-32), pC=l+128 (row1 col l+32).
__global__ __launch_bounds__(256, 8) void score_kernel(
    const float* __restrict__ x,
    const float* __restrict__ partials,
    float* __restrict__ out,
    int N) {
  __shared__ float ctx_s[D];
  const int tid = threadIdx.x;

  const f32x4* p4 = reinterpret_cast<const f32x4*>(partials);
  for (int t = tid; t < D; t += 256) {
    f32x4 v0 = p4[t * 2 + 0];
    f32x4 v1 = p4[t * 2 + 1];
    ctx_s[t] = (v0.x + v0.y + v0.z + v0.w) + (v1.x + v1.y + v1.z + v1.w);
  }
  __syncthreads();

  const float scale = 1.0f / (ctx_s[0] + EPS);
  const int lane = tid & 63;
  const int w = tid >> 6;
  const f32x4* c4 = reinterpret_cast<const f32x4*>(ctx_s);
  const f32x4 cvA = c4[lane];
  const f32x4 cvB = c4[(lane < 32) ? (lane + 64) : (lane - 32)];
  const f32x4 cvC = c4[lane + 32];
  const bool lo = (lane < 32);

  const f32x4* x4 = reinterpret_cast<const f32x4*>(x);
  const int waveId = blockIdx.x * 4 + w;    // 0..8191
  const int base = waveId * 8;              // 8 adjacent rows per wave

#pragma unroll
  for (int it = 0; it < 2; ++it) {
    const int r0 = base + it * 4;           // pairs (r0,r0+1), (r0+2,r0+3)
    const f32x4* q0 = x4 + (size_t)r0 * 96;
    const f32x4* q1 = q0 + 192;
    f32x4 a0 = ldnt(q0 + lane);
    f32x4 b0 = ldnt(q0 + 64 + lane);
    f32x4 c0 = ldnt(q0 + 128 + lane);
    f32x4 a1 = ldnt(q1 + lane);
    f32x4 b1 = ldnt(q1 + 64 + lane);
    f32x4 c1 = ldnt(q1 + 128 + lane);

    float t0 = dot4(b0, cvB);
    float t1 = dot4(b1, cvB);
    float sA0 = dot4(a0, cvA) + (lo ? t0 : 0.0f);
    float sB0 = dot4(c0, cvC) + (lo ? 0.0f : t0);
    float sA1 = dot4(a1, cvA) + (lo ? t1 : 0.0f);
    float sB1 = dot4(c1, cvC) + (lo ? 0.0f : t1);

#pragma unroll
    for (int off = 32; off > 0; off >>= 1) {
      sA0 += __shfl_down(sA0, off);
      sB0 += __shfl_down(sB0, off);
      sA1 += __shfl_down(sA1, off);
      sB1 += __shfl_down(sB1, off);
    }
    if (lane == 0) {
      out[r0 + 0] = sA0 * scale;
      out[r0 + 1] = sB0 * scale;
      out[r0 + 2] = sA1 * scale;
      out[r0 + 3] = sB1 * scale;
    }
  }
}

extern "C" void kernel_launch(void* const* d_in, const int* in_sizes, int n_in,
                              void* d_out, int out_size, void* d_ws, size_t ws_size,
                              hipStream_t stream) {
  const float* x = (const float*)d_in[0];  // [N, 384]
  const float* y = (const float*)d_in[1];  // [384]
  const float* z = (const float*)d_in[2];  // [384]
  const float* a = (const float*)d_in[3];  // [384, 384, 384]
  float* out = (float*)d_out;              // [N]

  const int N = in_sizes[0] / D;           // 65536
  float* partials = (float*)d_ws;          // D*P floats

  ctx_partial_kernel<<<D * P, THREADS_A, 0, stream>>>(a, y, z, partials);
  score_kernel<<<2048, 256, 0, stream>>>(x, partials, out, N);
}